// Round 4
// baseline (303.003 us; speedup 1.0000x reference)
//
#include <hip/hip_runtime.h>

// TangentSpaceLoss: loss = (1/B^2) sum_ij softmax_j(E E^T)_ij * ||v_i - v_j||^2
// B=8192, G=512, D=64.
//
// R3 post-mortem: 64x64 tiles were LDS-inst bound (~560 b128/block, 102
// cells/read; MfmaUtil 8.5%). R4: 128x128 tiles, 4x4 register blocking
// (256 cells/b128 read), register-prefetch double-buffered K-loop, LDS
// region reused between S phase (E h/r tiles) and G phase (V dbuf) to
// keep 2 blocks/CU.
//   S tile: fp16 MFMA + residual (E=h+r; s=hh'+hr'+rh', err ~1e-4)
//   G tile: fp16 MFMA, K=512
// Selection: s > min(ne_i,ne_j)-32 (safe superset; neglected mass 2.7e-11
// << 5.4e-10 tol). Softmax shift ne_i; diagonal w=1, wd=0 -> Z preinit 1.

#define B_CELLS 8192
#define G_GENES 512
#define D_LAT   64
#define SEL_T   32.0f
#define SR      72          // LDS row stride in halfs (b128 pattern 8-deep uniform)

typedef _Float16 half8 __attribute__((ext_vector_type(8)));
typedef float    f32x4 __attribute__((ext_vector_type(4)));

#define MFMA16(a, b, c) __builtin_amdgcn_mfma_f32_16x16x32_f16(a, b, c, 0, 0, 0)

// ---------------- K1: norms + fp16 (h + residual) casts -----------------
__global__ __launch_bounds__(256) void k_prep(
    const float* __restrict__ V, const float* __restrict__ E,
    float* __restrict__ n, float* __restrict__ ne, float* __restrict__ Z,
    _Float16* __restrict__ Eh, _Float16* __restrict__ Er,
    _Float16* __restrict__ Vh) {
    int row  = (blockIdx.x << 2) + (threadIdx.x >> 6);
    int lane = threadIdx.x & 63;
    const float* vr = V + (size_t)row * G_GENES;
    _Float16* vh = Vh + (size_t)row * G_GENES;
    float sn = 0.f;
#pragma unroll
    for (int k = 0; k < 8; ++k) {
        float x = vr[k * 64 + lane];
        vh[k * 64 + lane] = (_Float16)x;
        sn += x * x;
    }
    float el = E[row * D_LAT + lane];
    _Float16 hx = (_Float16)el;
    Eh[row * D_LAT + lane] = hx;
    Er[row * D_LAT + lane] = (_Float16)(el - (float)hx);
    float se = el * el;
#pragma unroll
    for (int m = 1; m < 64; m <<= 1) {
        sn += __shfl_xor(sn, m, 64);
        se += __shfl_xor(se, m, 64);
    }
    if (lane == 0) { n[row] = sn; ne[row] = se; Z[row] = 1.0f; }
}

// ---------------- K2: fused 128x128 tile kernel -------------------------
// 256 thr = 4 waves in 2x2 grid; wave tile 64x64 = 4x4 MFMA tiles.
// sM[4] regions: S phase = {hA, rA, hB, rB}; G phase = {A0, A1, B0, B1}.
__global__ __launch_bounds__(256, 2) void k_mega(
    const _Float16* __restrict__ Eh, const _Float16* __restrict__ Er,
    const _Float16* __restrict__ Vh,
    const float* __restrict__ ne, const float* __restrict__ nrm,
    float* __restrict__ Z, float* __restrict__ num) {
    int blk = blockIdx.x;
    int bx = blk & 63, by = blk >> 6;
    if (bx > by) return;                 // canonical: i-tile <= j-tile
    int i0 = bx << 7, j0 = by << 7;
    bool diag = (bx == by);

    __shared__ __align__(16) _Float16 sM[4][128 * SR];
    __shared__ float sNeI[128], sNeJ[128], sNI[128], sNJ[128];

    int tid = threadIdx.x;

    // ---- issue V chunk 0 prefetch (regs) ----
    const uint4* gVa = (const uint4*)(Vh + (size_t)i0 * G_GENES);  // 64 uint4/row
    const uint4* gVb = (const uint4*)(Vh + (size_t)j0 * G_GENES);
    uint4 pa[4], pb[4];
#pragma unroll
    for (int k = 0; k < 4; ++k) {
        int t = tid + (k << 8);
        int r = t >> 3, cc = t & 7;
        pa[k] = gVa[(size_t)r * 64 + cc];
        pb[k] = gVb[(size_t)r * 64 + cc];
    }

    // ---- stage E h/r tiles (128 rows x 8 uint4 each) ----
    {
        const uint4* g0 = (const uint4*)(Eh + (size_t)i0 * D_LAT);
        const uint4* g1 = (const uint4*)(Er + (size_t)i0 * D_LAT);
        const uint4* g2 = (const uint4*)(Eh + (size_t)j0 * D_LAT);
        const uint4* g3 = (const uint4*)(Er + (size_t)j0 * D_LAT);
        uint4* l0 = (uint4*)sM[0]; uint4* l1 = (uint4*)sM[1];
        uint4* l2 = (uint4*)sM[2]; uint4* l3 = (uint4*)sM[3];
        for (int t = tid; t < 1024; t += 256) {
            int r = t >> 3, cc = t & 7;
            l0[r * 9 + cc] = g0[r * 8 + cc];
            l1[r * 9 + cc] = g1[r * 8 + cc];
            l2[r * 9 + cc] = g2[r * 8 + cc];
            l3[r * 9 + cc] = g3[r * 8 + cc];
        }
        if (tid < 128) { sNeI[tid] = ne[i0 + tid]; sNI[tid] = nrm[i0 + tid]; }
        else { sNeJ[tid - 128] = ne[j0 + tid - 128]; sNJ[tid - 128] = nrm[j0 + tid - 128]; }
    }
    __syncthreads();

    int wave = tid >> 6, lane = tid & 63;
    int m = lane & 15, quad = lane >> 4;
    int wi = wave & 1, wj = wave >> 1;
    int ia = (wi << 6) + m;              // a-frag row = ia + im*16
    int ja = (wj << 6) + m;              // b-frag row (= C col) = ja + jn*16

    // ---- S phase: hh' + hr' + rh' ----
    f32x4 sacc[4][4];
    {
        half8 ah[4][2], ar_[4][2];
#pragma unroll
        for (int im = 0; im < 4; ++im) {
            int row = ia + im * 16;
            ah[im][0]  = *(const half8*)(sM[0] + row * SR + quad * 8);
            ah[im][1]  = *(const half8*)(sM[0] + row * SR + 32 + quad * 8);
            ar_[im][0] = *(const half8*)(sM[1] + row * SR + quad * 8);
            ar_[im][1] = *(const half8*)(sM[1] + row * SR + 32 + quad * 8);
        }
#pragma unroll
        for (int jn = 0; jn < 4; ++jn) {
            int col = ja + jn * 16;
            half8 bh0 = *(const half8*)(sM[2] + col * SR + quad * 8);
            half8 bh1 = *(const half8*)(sM[2] + col * SR + 32 + quad * 8);
            half8 br0 = *(const half8*)(sM[3] + col * SR + quad * 8);
            half8 br1 = *(const half8*)(sM[3] + col * SR + 32 + quad * 8);
#pragma unroll
            for (int im = 0; im < 4; ++im) {
                f32x4 acc = {0.f, 0.f, 0.f, 0.f};
                acc = MFMA16(ah[im][0], bh0, acc);
                acc = MFMA16(ah[im][1], bh1, acc);
                acc = MFMA16(ah[im][0], br0, acc);
                acc = MFMA16(ah[im][1], br1, acc);
                acc = MFMA16(ar_[im][0], bh0, acc);
                acc = MFMA16(ar_[im][1], bh1, acc);
                sacc[im][jn] = acc;
            }
        }
    }
    __syncthreads();                     // S reads done; sM reusable for V

    // ---- G phase: K=512 in 8 chunks of 64, reg-prefetch + LDS dbuf ----
    // buf b: A in sM[b], B in sM[2+b]
    f32x4 gacc[4][4] = {};
    {
        // write chunk 0, prefetch chunk 1
        uint4* la = (uint4*)sM[0]; uint4* lb = (uint4*)sM[2];
#pragma unroll
        for (int k = 0; k < 4; ++k) {
            int t = tid + (k << 8);
            int r = t >> 3, cc = t & 7;
            la[r * 9 + cc] = pa[k];
            lb[r * 9 + cc] = pb[k];
        }
#pragma unroll
        for (int k = 0; k < 4; ++k) {
            int t = tid + (k << 8);
            int r = t >> 3, cc = t & 7;
            pa[k] = gVa[(size_t)r * 64 + 8 + cc];
            pb[k] = gVb[(size_t)r * 64 + 8 + cc];
        }
    }
    __syncthreads();

    for (int c = 0; c < 8; ++c) {
        const _Float16* A  = sM[c & 1];
        const _Float16* Bt = sM[2 + (c & 1)];
        if (c < 7) {
            // write chunk c+1 into the other buffer (safe: barrier at end of
            // prev iter separates it from reads of that buffer)
            uint4* la = (uint4*)sM[(c + 1) & 1];
            uint4* lb = (uint4*)sM[2 + ((c + 1) & 1)];
#pragma unroll
            for (int k = 0; k < 4; ++k) {
                int t = tid + (k << 8);
                int r = t >> 3, cc = t & 7;
                la[r * 9 + cc] = pa[k];
                lb[r * 9 + cc] = pb[k];
            }
            if (c < 6) {
#pragma unroll
                for (int k = 0; k < 4; ++k) {
                    int t = tid + (k << 8);
                    int r = t >> 3, cc = t & 7;
                    pa[k] = gVa[(size_t)r * 64 + (c + 2) * 8 + cc];
                    pb[k] = gVb[(size_t)r * 64 + (c + 2) * 8 + cc];
                }
            }
        }
        half8 va[4][2];
#pragma unroll
        for (int im = 0; im < 4; ++im) {
            int row = ia + im * 16;
            va[im][0] = *(const half8*)(A + row * SR + quad * 8);
            va[im][1] = *(const half8*)(A + row * SR + 32 + quad * 8);
        }
#pragma unroll
        for (int jn = 0; jn < 4; ++jn) {
            int col = ja + jn * 16;
            half8 vb0 = *(const half8*)(Bt + col * SR + quad * 8);
            half8 vb1 = *(const half8*)(Bt + col * SR + 32 + quad * 8);
#pragma unroll
            for (int im = 0; im < 4; ++im) {
                gacc[im][jn] = MFMA16(va[im][0], vb0, gacc[im][jn]);
                gacc[im][jn] = MFMA16(va[im][1], vb1, gacc[im][jn]);
            }
        }
        __syncthreads();
    }

    // ---- epilogue: select + weights + row/col reduce + atomics ----
    float zi[4][4] = {}, ni_[4][4] = {};
    float zj[4] = {}, nj_[4] = {};
#pragma unroll
    for (int jn = 0; jn < 4; ++jn) {
        int jl = (wj << 6) + jn * 16 + m;
        int jg = j0 + jl;
        float nej = sNeJ[jl], nnj = sNJ[jl];
#pragma unroll
        for (int im = 0; im < 4; ++im) {
            f32x4 s4 = sacc[im][jn], g4 = gacc[im][jn];
#pragma unroll
            for (int r = 0; r < 4; ++r) {
                int il = (wi << 6) + im * 16 + quad * 4 + r;
                int ig = i0 + il;
                float nei = sNeI[il], nni = sNI[il];
                float s = s4[r];
                bool pred = (s > fminf(nei, nej) - SEL_T) && (!diag || ig < jg);
                if (pred) {
                    float wiw = __expf(s - nei);
                    float wjw = __expf(s - nej);
                    float wd = nni + nnj - 2.f * g4[r];
                    zi[im][r] += wiw;  ni_[im][r] += wiw * wd;
                    zj[jn]    += wjw;  nj_[jn]    += wjw * wd;
                }
            }
        }
    }
    // i-side: reduce over the 16 m-lanes (rows exclusive to quad-group)
#pragma unroll
    for (int msk = 1; msk < 16; msk <<= 1) {
#pragma unroll
        for (int im = 0; im < 4; ++im)
#pragma unroll
            for (int r = 0; r < 4; ++r) {
                zi[im][r]  += __shfl_xor(zi[im][r],  msk, 64);
                ni_[im][r] += __shfl_xor(ni_[im][r], msk, 64);
            }
    }
    if (m == 0) {
#pragma unroll
        for (int im = 0; im < 4; ++im)
#pragma unroll
            for (int r = 0; r < 4; ++r) {
                int row = i0 + (wi << 6) + im * 16 + quad * 4 + r;
                atomicAdd(Z + row,   zi[im][r]);
                atomicAdd(num + row, ni_[im][r]);
            }
    }
    // j-side: reduce over quads
#pragma unroll
    for (int msk = 16; msk < 64; msk <<= 1) {
#pragma unroll
        for (int jn = 0; jn < 4; ++jn) {
            zj[jn]  += __shfl_xor(zj[jn],  msk, 64);
            nj_[jn] += __shfl_xor(nj_[jn], msk, 64);
        }
    }
    if (quad == 0) {
#pragma unroll
        for (int jn = 0; jn < 4; ++jn) {
            int col = j0 + (wj << 6) + jn * 16 + m;
            atomicAdd(Z + col,   zj[jn]);
            atomicAdd(num + col, nj_[jn]);
        }
    }
}

// ---------------- K3a/K3b: final reduction ------------------------------
__global__ __launch_bounds__(256) void k_final1(
    const float* __restrict__ Z, const float* __restrict__ num,
    double* __restrict__ part) {
    int i = (blockIdx.x << 8) + threadIdx.x;
    __shared__ double sd[256];
    sd[threadIdx.x] = (double)num[i] / (double)Z[i];   // Z >= 1 (diag w=1)
    __syncthreads();
    for (int s = 128; s > 0; s >>= 1) {
        if (threadIdx.x < s) sd[threadIdx.x] += sd[threadIdx.x + s];
        __syncthreads();
    }
    if (threadIdx.x == 0) part[blockIdx.x] = sd[0];
}

__global__ void k_final2(const double* __restrict__ part, float* __restrict__ out) {
    if (threadIdx.x == 0) {
        double a = 0.0;
        for (int k = 0; k < 32; ++k) a += part[k];
        out[0] = (float)(a / 67108864.0);              // / B^2
    }
}

// ---------------- host launcher -----------------------------------------
extern "C" void kernel_launch(void* const* d_in, const int* in_sizes, int n_in,
                              void* d_out, int out_size, void* d_ws, size_t ws_size,
                              hipStream_t stream) {
    const float* V = (const float*)d_in[0];   // [8192, 512] f32
    const float* E = (const float*)d_in[1];   // [8192, 64]  f32
    float* out = (float*)d_out;
    char* ws = (char*)d_ws;

    float*     n_   = (float*)(ws + 0);          // 32 KB
    float*     ne   = (float*)(ws + 32768);      // 32 KB
    float*     Z    = (float*)(ws + 65536);      // 32 KB (init 1.0 in k_prep)
    float*     num  = (float*)(ws + 98304);      // 32 KB (memset 0)
    double*    part = (double*)(ws + 131072);    // 256 B
    _Float16*  Eh   = (_Float16*)(ws + 131584);  // 1 MB
    _Float16*  Er   = (_Float16*)(ws + 1180160); // 1 MB
    _Float16*  Vh   = (_Float16*)(ws + 2228736); // 8 MB

    hipMemsetAsync((void*)num, 0, 32768, stream);

    k_prep  <<<2048, 256, 0, stream>>>(V, E, n_, ne, Z, Eh, Er, Vh);
    k_mega  <<<4096, 256, 0, stream>>>(Eh, Er, Vh, ne, n_, Z, num);
    k_final1<<<32, 256, 0, stream>>>(Z, num, part);
    k_final2<<<1, 64, 0, stream>>>(part, out);
}

// Round 5
// 268.216 us; speedup vs baseline: 1.1297x; 1.1297x over previous
//
#include <hip/hip_runtime.h>

// TangentSpaceLoss: loss = (1/B^2) sum_ij softmax_j(E E^T)_ij * ||v_i - v_j||^2
// B=8192, G=512, D=64.
//
// R4 post-mortem: sacc (64 VGPRs) live across the whole G K-loop forced a
// scratch spill (WRITE_SIZE 20->167 MB). R5: G-phase FIRST (gacc -> AGPRs),
// S-phase LAST with fragments loaded DIRECTLY from global (Eh/Er are L2-hot;
// frag = 16 contiguous bytes at row*64+quad*8), epilogue immediately after.
// No E LDS staging; LDS holds only the V double-buffer. Triangular grid
// (2080 blocks, closed-form decode).
//   S tile: fp16 MFMA + residual (E=h+r; s=hh'+hr'+rh', err ~1e-4)
//   G tile: fp16 MFMA, K=512, reg-prefetch + LDS dbuf
// Selection: s > min(ne_i,ne_j)-32 (safe superset; neglected mass 2.7e-11
// << 5.4e-10 tol). Softmax shift ne_i; diagonal w=1, wd=0 -> Z preinit 1.

#define B_CELLS 8192
#define G_GENES 512
#define D_LAT   64
#define SEL_T   32.0f
#define SR      72          // LDS row stride in halfs

typedef _Float16 half8 __attribute__((ext_vector_type(8)));
typedef float    f32x4 __attribute__((ext_vector_type(4)));

#define MFMA16(a, b, c) __builtin_amdgcn_mfma_f32_16x16x32_f16(a, b, c, 0, 0, 0)

// ---------------- K1: norms + fp16 (h + residual) casts -----------------
__global__ __launch_bounds__(256) void k_prep(
    const float* __restrict__ V, const float* __restrict__ E,
    float* __restrict__ n, float* __restrict__ ne, float* __restrict__ Z,
    _Float16* __restrict__ Eh, _Float16* __restrict__ Er,
    _Float16* __restrict__ Vh) {
    int row  = (blockIdx.x << 2) + (threadIdx.x >> 6);
    int lane = threadIdx.x & 63;
    const float* vr = V + (size_t)row * G_GENES;
    _Float16* vh = Vh + (size_t)row * G_GENES;
    float sn = 0.f;
#pragma unroll
    for (int k = 0; k < 8; ++k) {
        float x = vr[k * 64 + lane];
        vh[k * 64 + lane] = (_Float16)x;
        sn += x * x;
    }
    float el = E[row * D_LAT + lane];
    _Float16 hx = (_Float16)el;
    Eh[row * D_LAT + lane] = hx;
    Er[row * D_LAT + lane] = (_Float16)(el - (float)hx);
    float se = el * el;
#pragma unroll
    for (int m = 1; m < 64; m <<= 1) {
        sn += __shfl_xor(sn, m, 64);
        se += __shfl_xor(se, m, 64);
    }
    if (lane == 0) { n[row] = sn; ne[row] = se; Z[row] = 1.0f; }
}

// ---------------- K2: fused 128x128 tile kernel -------------------------
// 256 thr = 4 waves in 2x2 grid; wave tile 64x64 = 4x4 MFMA tiles.
__global__ __launch_bounds__(256, 2) void k_mega(
    const _Float16* __restrict__ Eh, const _Float16* __restrict__ Er,
    const _Float16* __restrict__ Vh,
    const float* __restrict__ ne, const float* __restrict__ nrm,
    float* __restrict__ Z, float* __restrict__ num) {
    // triangular decode: blk -> (bx <= by)
    int blk = blockIdx.x;
    int by = (int)((sqrtf(8.f * (float)blk + 1.f) - 1.f) * 0.5f);
    while ((by + 1) * (by + 2) / 2 <= blk) ++by;
    while (by * (by + 1) / 2 > blk) --by;
    int bx = blk - by * (by + 1) / 2;
    int i0 = bx << 7, j0 = by << 7;
    bool diag = (bx == by);

    __shared__ __align__(16) _Float16 sA[2][128 * SR];
    __shared__ __align__(16) _Float16 sB[2][128 * SR];
    __shared__ float sNeI[128], sNeJ[128], sNI[128], sNJ[128];

    int tid = threadIdx.x;
    int wave = tid >> 6, lane = tid & 63;
    int m = lane & 15, quad = lane >> 4;
    int wi = wave & 1, wj = wave >> 1;
    int ia = (wi << 6) + m;              // a rows = ia + im*16
    int ja = (wj << 6) + m;              // b rows (C cols) = ja + jn*16

    const uint4* gVa = (const uint4*)(Vh + (size_t)i0 * G_GENES);  // 64 u4/row
    const uint4* gVb = (const uint4*)(Vh + (size_t)j0 * G_GENES);

    // prefetch chunk 0 into regs
    uint4 pa[4], pb[4];
#pragma unroll
    for (int k = 0; k < 4; ++k) {
        int t = tid + (k << 8);
        int r = t >> 3, cc = t & 7;
        pa[k] = gVa[(size_t)r * 64 + cc];
        pb[k] = gVb[(size_t)r * 64 + cc];
    }
    if (tid < 128) { sNeI[tid] = ne[i0 + tid]; sNI[tid] = nrm[i0 + tid]; }
    else { sNeJ[tid - 128] = ne[j0 + tid - 128]; sNJ[tid - 128] = nrm[j0 + tid - 128]; }

    // write chunk 0, prefetch chunk 1
    {
        uint4* la = (uint4*)sA[0]; uint4* lb = (uint4*)sB[0];
#pragma unroll
        for (int k = 0; k < 4; ++k) {
            int t = tid + (k << 8);
            int r = t >> 3, cc = t & 7;
            la[r * 9 + cc] = pa[k];
            lb[r * 9 + cc] = pb[k];
        }
#pragma unroll
        for (int k = 0; k < 4; ++k) {
            int t = tid + (k << 8);
            int r = t >> 3, cc = t & 7;
            pa[k] = gVa[(size_t)r * 64 + 8 + cc];
            pb[k] = gVb[(size_t)r * 64 + 8 + cc];
        }
    }
    __syncthreads();

    // ---- G phase: K=512 in 8 chunks, reg-prefetch + LDS dbuf ----
    f32x4 gacc[4][4] = {};
    for (int c = 0; c < 8; ++c) {
        const _Float16* A  = sA[c & 1];
        const _Float16* Bt = sB[c & 1];
        if (c < 7) {
            uint4* la = (uint4*)sA[(c + 1) & 1];
            uint4* lb = (uint4*)sB[(c + 1) & 1];
#pragma unroll
            for (int k = 0; k < 4; ++k) {
                int t = tid + (k << 8);
                int r = t >> 3, cc = t & 7;
                la[r * 9 + cc] = pa[k];
                lb[r * 9 + cc] = pb[k];
            }
            if (c < 6) {
#pragma unroll
                for (int k = 0; k < 4; ++k) {
                    int t = tid + (k << 8);
                    int r = t >> 3, cc = t & 7;
                    pa[k] = gVa[(size_t)r * 64 + (c + 2) * 8 + cc];
                    pb[k] = gVb[(size_t)r * 64 + (c + 2) * 8 + cc];
                }
            }
        }
        half8 va[4][2];
#pragma unroll
        for (int im = 0; im < 4; ++im) {
            int row = ia + im * 16;
            va[im][0] = *(const half8*)(A + row * SR + quad * 8);
            va[im][1] = *(const half8*)(A + row * SR + 32 + quad * 8);
        }
#pragma unroll
        for (int jn = 0; jn < 4; ++jn) {
            int col = ja + jn * 16;
            half8 vb0 = *(const half8*)(Bt + col * SR + quad * 8);
            half8 vb1 = *(const half8*)(Bt + col * SR + 32 + quad * 8);
#pragma unroll
            for (int im = 0; im < 4; ++im) {
                gacc[im][jn] = MFMA16(va[im][0], vb0, gacc[im][jn]);
                gacc[im][jn] = MFMA16(va[im][1], vb1, gacc[im][jn]);
            }
        }
        if (c < 7) __syncthreads();
    }

    // ---- S phase: direct-global fragments, hh' + hr' + rh' ----
    f32x4 sacc[4][4];
    {
        const _Float16* gAh = Eh + (size_t)i0 * D_LAT;
        const _Float16* gAr = Er + (size_t)i0 * D_LAT;
        const _Float16* gBh = Eh + (size_t)j0 * D_LAT;
        const _Float16* gBr = Er + (size_t)j0 * D_LAT;
#pragma unroll
        for (int im = 0; im < 4; ++im) {
            int row = ia + im * 16;
            half8 ah0 = *(const half8*)(gAh + (size_t)row * 64 + quad * 8);
            half8 ah1 = *(const half8*)(gAh + (size_t)row * 64 + 32 + quad * 8);
            half8 ar0 = *(const half8*)(gAr + (size_t)row * 64 + quad * 8);
            half8 ar1 = *(const half8*)(gAr + (size_t)row * 64 + 32 + quad * 8);
#pragma unroll
            for (int jn = 0; jn < 4; ++jn) {
                int col = ja + jn * 16;
                half8 bh0 = *(const half8*)(gBh + (size_t)col * 64 + quad * 8);
                half8 bh1 = *(const half8*)(gBh + (size_t)col * 64 + 32 + quad * 8);
                half8 br0 = *(const half8*)(gBr + (size_t)col * 64 + quad * 8);
                half8 br1 = *(const half8*)(gBr + (size_t)col * 64 + 32 + quad * 8);
                f32x4 acc = {0.f, 0.f, 0.f, 0.f};
                acc = MFMA16(ah0, bh0, acc);
                acc = MFMA16(ah1, bh1, acc);
                acc = MFMA16(ah0, br0, acc);
                acc = MFMA16(ah1, br1, acc);
                acc = MFMA16(ar0, bh0, acc);
                acc = MFMA16(ar1, bh1, acc);
                sacc[im][jn] = acc;
            }
        }
    }

    // ---- epilogue: select + weights + row/col reduce + atomics ----
    float zi[4][4] = {}, ni_[4][4] = {};
    float zj[4] = {}, nj_[4] = {};
#pragma unroll
    for (int jn = 0; jn < 4; ++jn) {
        int jl = (wj << 6) + jn * 16 + m;
        int jg = j0 + jl;
        float nej = sNeJ[jl], nnj = sNJ[jl];
#pragma unroll
        for (int im = 0; im < 4; ++im) {
            f32x4 s4 = sacc[im][jn], g4 = gacc[im][jn];
#pragma unroll
            for (int r = 0; r < 4; ++r) {
                int il = (wi << 6) + im * 16 + quad * 4 + r;
                int ig = i0 + il;
                float nei = sNeI[il], nni = sNI[il];
                float s = s4[r];
                bool pred = (s > fminf(nei, nej) - SEL_T) && (!diag || ig < jg);
                if (pred) {
                    float wiw = __expf(s - nei);
                    float wjw = __expf(s - nej);
                    float wd = nni + nnj - 2.f * g4[r];
                    zi[im][r] += wiw;  ni_[im][r] += wiw * wd;
                    zj[jn]    += wjw;  nj_[jn]    += wjw * wd;
                }
            }
        }
    }
#pragma unroll
    for (int msk = 1; msk < 16; msk <<= 1) {
#pragma unroll
        for (int im = 0; im < 4; ++im)
#pragma unroll
            for (int r = 0; r < 4; ++r) {
                zi[im][r]  += __shfl_xor(zi[im][r],  msk, 64);
                ni_[im][r] += __shfl_xor(ni_[im][r], msk, 64);
            }
    }
    if (m == 0) {
#pragma unroll
        for (int im = 0; im < 4; ++im)
#pragma unroll
            for (int r = 0; r < 4; ++r) {
                int row = i0 + (wi << 6) + im * 16 + quad * 4 + r;
                atomicAdd(Z + row,   zi[im][r]);
                atomicAdd(num + row, ni_[im][r]);
            }
    }
#pragma unroll
    for (int msk = 16; msk < 64; msk <<= 1) {
#pragma unroll
        for (int jn = 0; jn < 4; ++jn) {
            zj[jn]  += __shfl_xor(zj[jn],  msk, 64);
            nj_[jn] += __shfl_xor(nj_[jn], msk, 64);
        }
    }
    if (quad == 0) {
#pragma unroll
        for (int jn = 0; jn < 4; ++jn) {
            int col = j0 + (wj << 6) + jn * 16 + m;
            atomicAdd(Z + col,   zj[jn]);
            atomicAdd(num + col, nj_[jn]);
        }
    }
}

// ---------------- K3a/K3b: final reduction ------------------------------
__global__ __launch_bounds__(256) void k_final1(
    const float* __restrict__ Z, const float* __restrict__ num,
    double* __restrict__ part) {
    int i = (blockIdx.x << 8) + threadIdx.x;
    __shared__ double sd[256];
    sd[threadIdx.x] = (double)num[i] / (double)Z[i];   // Z >= 1 (diag w=1)
    __syncthreads();
    for (int s = 128; s > 0; s >>= 1) {
        if (threadIdx.x < s) sd[threadIdx.x] += sd[threadIdx.x + s];
        __syncthreads();
    }
    if (threadIdx.x == 0) part[blockIdx.x] = sd[0];
}

__global__ void k_final2(const double* __restrict__ part, float* __restrict__ out) {
    if (threadIdx.x == 0) {
        double a = 0.0;
        for (int k = 0; k < 32; ++k) a += part[k];
        out[0] = (float)(a / 67108864.0);              // / B^2
    }
}

// ---------------- host launcher -----------------------------------------
extern "C" void kernel_launch(void* const* d_in, const int* in_sizes, int n_in,
                              void* d_out, int out_size, void* d_ws, size_t ws_size,
                              hipStream_t stream) {
    const float* V = (const float*)d_in[0];   // [8192, 512] f32
    const float* E = (const float*)d_in[1];   // [8192, 64]  f32
    float* out = (float*)d_out;
    char* ws = (char*)d_ws;

    float*     n_   = (float*)(ws + 0);          // 32 KB
    float*     ne   = (float*)(ws + 32768);      // 32 KB
    float*     Z    = (float*)(ws + 65536);      // 32 KB (init 1.0 in k_prep)
    float*     num  = (float*)(ws + 98304);      // 32 KB (memset 0)
    double*    part = (double*)(ws + 131072);    // 256 B
    _Float16*  Eh   = (_Float16*)(ws + 131584);  // 1 MB
    _Float16*  Er   = (_Float16*)(ws + 1180160); // 1 MB
    _Float16*  Vh   = (_Float16*)(ws + 2228736); // 8 MB

    hipMemsetAsync((void*)num, 0, 32768, stream);

    k_prep  <<<2048, 256, 0, stream>>>(V, E, n_, ne, Z, Eh, Er, Vh);
    k_mega  <<<2080, 256, 0, stream>>>(Eh, Er, Vh, ne, n_, Z, num);
    k_final1<<<32, 256, 0, stream>>>(Z, num, part);
    k_final2<<<1, 64, 0, stream>>>(part, out);
}

// Round 6
// 267.513 us; speedup vs baseline: 1.1327x; 1.0026x over previous
//
#include <hip/hip_runtime.h>

// TangentSpaceLoss: loss = (1/B^2) sum_ij softmax_j(E E^T)_ij * ||v_i - v_j||^2
// B=8192, G=512, D=64.
//
// R5 post-mortem: sacc[4][4]+gacc[4][4] simultaneously live at epilogue ->
// 220+ MB scratch spill (WRITE 234 MB, FETCH 183 MB; kernel = scratch-BW
// bound at 2.07 TB/s). R6: NEVER materialize sacc — S-phase MFMAs are fused
// into the epilogue; each (im,jn) S-tile (4 regs) is consumed immediately
// against gacc[im][jn]. Peak live ~150 regs -> no spill.
//   G tile: fp16 MFMA, K=512, reg-prefetch + LDS dbuf (G phase FIRST,
//           gacc in AGPRs across the short S/epilogue phase)
//   S tile: fp16 MFMA + residual (E=h+r; s=hh'+hr'+rh', err ~1e-4),
//           fragments loaded directly from global (L1-hot, 16 KB/block)
// Selection: s > min(ne_i,ne_j)-32 (safe superset; neglected mass 2.7e-11
// << 5.4e-10 tol). Softmax shift ne_i; diagonal w=1, wd=0 -> Z preinit 1.
// Triangular grid: 2080 blocks, closed-form decode.

#define B_CELLS 8192
#define G_GENES 512
#define D_LAT   64
#define SEL_T   32.0f
#define SR      72          // LDS row stride in halfs

typedef _Float16 half8 __attribute__((ext_vector_type(8)));
typedef float    f32x4 __attribute__((ext_vector_type(4)));

#define MFMA16(a, b, c) __builtin_amdgcn_mfma_f32_16x16x32_f16(a, b, c, 0, 0, 0)

// ---------------- K1: norms + fp16 (h + residual) casts -----------------
__global__ __launch_bounds__(256) void k_prep(
    const float* __restrict__ V, const float* __restrict__ E,
    float* __restrict__ n, float* __restrict__ ne, float* __restrict__ Z,
    _Float16* __restrict__ Eh, _Float16* __restrict__ Er,
    _Float16* __restrict__ Vh) {
    int row  = (blockIdx.x << 2) + (threadIdx.x >> 6);
    int lane = threadIdx.x & 63;
    const float* vr = V + (size_t)row * G_GENES;
    _Float16* vh = Vh + (size_t)row * G_GENES;
    float sn = 0.f;
#pragma unroll
    for (int k = 0; k < 8; ++k) {
        float x = vr[k * 64 + lane];
        vh[k * 64 + lane] = (_Float16)x;
        sn += x * x;
    }
    float el = E[row * D_LAT + lane];
    _Float16 hx = (_Float16)el;
    Eh[row * D_LAT + lane] = hx;
    Er[row * D_LAT + lane] = (_Float16)(el - (float)hx);
    float se = el * el;
#pragma unroll
    for (int m = 1; m < 64; m <<= 1) {
        sn += __shfl_xor(sn, m, 64);
        se += __shfl_xor(se, m, 64);
    }
    if (lane == 0) { n[row] = sn; ne[row] = se; Z[row] = 1.0f; }
}

// ---------------- K2: fused 128x128 tile kernel -------------------------
// 256 thr = 4 waves in 2x2 grid; wave tile 64x64 = 4x4 MFMA tiles.
__global__ __launch_bounds__(256, 2) void k_mega(
    const _Float16* __restrict__ Eh, const _Float16* __restrict__ Er,
    const _Float16* __restrict__ Vh,
    const float* __restrict__ ne, const float* __restrict__ nrm,
    float* __restrict__ Z, float* __restrict__ num) {
    // triangular decode: blk -> (bx <= by)
    int blk = blockIdx.x;
    int by = (int)((sqrtf(8.f * (float)blk + 1.f) - 1.f) * 0.5f);
    while ((by + 1) * (by + 2) / 2 <= blk) ++by;
    while (by * (by + 1) / 2 > blk) --by;
    int bx = blk - by * (by + 1) / 2;
    int i0 = bx << 7, j0 = by << 7;
    bool diag = (bx == by);

    __shared__ __align__(16) _Float16 sA[2][128 * SR];
    __shared__ __align__(16) _Float16 sB[2][128 * SR];
    __shared__ float sNeI[128], sNeJ[128], sNI[128], sNJ[128];

    int tid = threadIdx.x;
    int wave = tid >> 6, lane = tid & 63;
    int m = lane & 15, quad = lane >> 4;
    int wi = wave & 1, wj = wave >> 1;
    int ia = (wi << 6) + m;              // a rows = ia + im*16
    int ja = (wj << 6) + m;              // b rows (C cols) = ja + jn*16

    const uint4* gVa = (const uint4*)(Vh + (size_t)i0 * G_GENES);  // 64 u4/row
    const uint4* gVb = (const uint4*)(Vh + (size_t)j0 * G_GENES);

    // prefetch chunk 0 into regs
    uint4 pa[4], pb[4];
#pragma unroll
    for (int k = 0; k < 4; ++k) {
        int t = tid + (k << 8);
        int r = t >> 3, cc = t & 7;
        pa[k] = gVa[(size_t)r * 64 + cc];
        pb[k] = gVb[(size_t)r * 64 + cc];
    }
    if (tid < 128) { sNeI[tid] = ne[i0 + tid]; sNI[tid] = nrm[i0 + tid]; }
    else { sNeJ[tid - 128] = ne[j0 + tid - 128]; sNJ[tid - 128] = nrm[j0 + tid - 128]; }

    // write chunk 0, prefetch chunk 1
    {
        uint4* la = (uint4*)sA[0]; uint4* lb = (uint4*)sB[0];
#pragma unroll
        for (int k = 0; k < 4; ++k) {
            int t = tid + (k << 8);
            int r = t >> 3, cc = t & 7;
            la[r * 9 + cc] = pa[k];
            lb[r * 9 + cc] = pb[k];
        }
#pragma unroll
        for (int k = 0; k < 4; ++k) {
            int t = tid + (k << 8);
            int r = t >> 3, cc = t & 7;
            pa[k] = gVa[(size_t)r * 64 + 8 + cc];
            pb[k] = gVb[(size_t)r * 64 + 8 + cc];
        }
    }
    __syncthreads();

    // ---- G phase: K=512 in 8 chunks, reg-prefetch + LDS dbuf ----
    f32x4 gacc[4][4] = {};
    for (int c = 0; c < 8; ++c) {
        const _Float16* A  = sA[c & 1];
        const _Float16* Bt = sB[c & 1];
        if (c < 7) {
            uint4* la = (uint4*)sA[(c + 1) & 1];
            uint4* lb = (uint4*)sB[(c + 1) & 1];
#pragma unroll
            for (int k = 0; k < 4; ++k) {
                int t = tid + (k << 8);
                int r = t >> 3, cc = t & 7;
                la[r * 9 + cc] = pa[k];
                lb[r * 9 + cc] = pb[k];
            }
            if (c < 6) {
#pragma unroll
                for (int k = 0; k < 4; ++k) {
                    int t = tid + (k << 8);
                    int r = t >> 3, cc = t & 7;
                    pa[k] = gVa[(size_t)r * 64 + (c + 2) * 8 + cc];
                    pb[k] = gVb[(size_t)r * 64 + (c + 2) * 8 + cc];
                }
            }
        }
        half8 va[4][2];
#pragma unroll
        for (int im = 0; im < 4; ++im) {
            int row = ia + im * 16;
            va[im][0] = *(const half8*)(A + row * SR + quad * 8);
            va[im][1] = *(const half8*)(A + row * SR + 32 + quad * 8);
        }
#pragma unroll
        for (int jn = 0; jn < 4; ++jn) {
            int col = ja + jn * 16;
            half8 vb0 = *(const half8*)(Bt + col * SR + quad * 8);
            half8 vb1 = *(const half8*)(Bt + col * SR + 32 + quad * 8);
#pragma unroll
            for (int im = 0; im < 4; ++im) {
                gacc[im][jn] = MFMA16(va[im][0], vb0, gacc[im][jn]);
                gacc[im][jn] = MFMA16(va[im][1], vb1, gacc[im][jn]);
            }
        }
        if (c < 7) __syncthreads();
    }

    // ---- fused S phase + epilogue: sacc never materialized ----
    float zi[4][4] = {}, ni_[4][4] = {};
    float zj[4] = {}, nj_[4] = {};
    {
        const _Float16* gAh = Eh + (size_t)i0 * D_LAT;
        const _Float16* gAr = Er + (size_t)i0 * D_LAT;
        const _Float16* gBh = Eh + (size_t)j0 * D_LAT;
        const _Float16* gBr = Er + (size_t)j0 * D_LAT;
#pragma unroll
        for (int im = 0; im < 4; ++im) {
            int row = ia + im * 16;
            half8 ah0 = *(const half8*)(gAh + (size_t)row * 64 + quad * 8);
            half8 ah1 = *(const half8*)(gAh + (size_t)row * 64 + 32 + quad * 8);
            half8 ar0 = *(const half8*)(gAr + (size_t)row * 64 + quad * 8);
            half8 ar1 = *(const half8*)(gAr + (size_t)row * 64 + 32 + quad * 8);
#pragma unroll
            for (int jn = 0; jn < 4; ++jn) {
                int col = ja + jn * 16;
                half8 bh0 = *(const half8*)(gBh + (size_t)col * 64 + quad * 8);
                half8 bh1 = *(const half8*)(gBh + (size_t)col * 64 + 32 + quad * 8);
                half8 br0 = *(const half8*)(gBr + (size_t)col * 64 + quad * 8);
                half8 br1 = *(const half8*)(gBr + (size_t)col * 64 + 32 + quad * 8);
                f32x4 acc = {0.f, 0.f, 0.f, 0.f};
                acc = MFMA16(ah0, bh0, acc);
                acc = MFMA16(ah1, bh1, acc);
                acc = MFMA16(ah0, br0, acc);
                acc = MFMA16(ah1, br1, acc);
                acc = MFMA16(ar0, bh0, acc);
                acc = MFMA16(ar1, bh1, acc);
                // consume immediately
                int jl = (wj << 6) + jn * 16 + m;
                int jg = j0 + jl;
                float nej = sNeJ[jl], nnj = sNJ[jl];
                f32x4 g4 = gacc[im][jn];
#pragma unroll
                for (int r = 0; r < 4; ++r) {
                    int il = (wi << 6) + im * 16 + quad * 4 + r;
                    int ig = i0 + il;
                    float nei = sNeI[il], nni = sNI[il];
                    float s = acc[r];
                    bool pred = (s > fminf(nei, nej) - SEL_T) && (!diag || ig < jg);
                    if (pred) {
                        float wiw = __expf(s - nei);
                        float wjw = __expf(s - nej);
                        float wd = nni + nnj - 2.f * g4[r];
                        zi[im][r] += wiw;  ni_[im][r] += wiw * wd;
                        zj[jn]    += wjw;  nj_[jn]    += wjw * wd;
                    }
                }
            }
        }
    }

    // ---- reductions + atomics ----
#pragma unroll
    for (int msk = 1; msk < 16; msk <<= 1) {
#pragma unroll
        for (int im = 0; im < 4; ++im)
#pragma unroll
            for (int r = 0; r < 4; ++r) {
                zi[im][r]  += __shfl_xor(zi[im][r],  msk, 64);
                ni_[im][r] += __shfl_xor(ni_[im][r], msk, 64);
            }
    }
    if (m == 0) {
#pragma unroll
        for (int im = 0; im < 4; ++im)
#pragma unroll
            for (int r = 0; r < 4; ++r) {
                int row = i0 + (wi << 6) + im * 16 + quad * 4 + r;
                atomicAdd(Z + row,   zi[im][r]);
                atomicAdd(num + row, ni_[im][r]);
            }
    }
#pragma unroll
    for (int msk = 16; msk < 64; msk <<= 1) {
#pragma unroll
        for (int jn = 0; jn < 4; ++jn) {
            zj[jn]  += __shfl_xor(zj[jn],  msk, 64);
            nj_[jn] += __shfl_xor(nj_[jn], msk, 64);
        }
    }
    if (quad == 0) {
#pragma unroll
        for (int jn = 0; jn < 4; ++jn) {
            int col = j0 + (wj << 6) + jn * 16 + m;
            atomicAdd(Z + col,   zj[jn]);
            atomicAdd(num + col, nj_[jn]);
        }
    }
}

// ---------------- K3a/K3b: final reduction ------------------------------
__global__ __launch_bounds__(256) void k_final1(
    const float* __restrict__ Z, const float* __restrict__ num,
    double* __restrict__ part) {
    int i = (blockIdx.x << 8) + threadIdx.x;
    __shared__ double sd[256];
    sd[threadIdx.x] = (double)num[i] / (double)Z[i];   // Z >= 1 (diag w=1)
    __syncthreads();
    for (int s = 128; s > 0; s >>= 1) {
        if (threadIdx.x < s) sd[threadIdx.x] += sd[threadIdx.x + s];
        __syncthreads();
    }
    if (threadIdx.x == 0) part[blockIdx.x] = sd[0];
}

__global__ void k_final2(const double* __restrict__ part, float* __restrict__ out) {
    if (threadIdx.x == 0) {
        double a = 0.0;
        for (int k = 0; k < 32; ++k) a += part[k];
        out[0] = (float)(a / 67108864.0);              // / B^2
    }
}

// ---------------- host launcher -----------------------------------------
extern "C" void kernel_launch(void* const* d_in, const int* in_sizes, int n_in,
                              void* d_out, int out_size, void* d_ws, size_t ws_size,
                              hipStream_t stream) {
    const float* V = (const float*)d_in[0];   // [8192, 512] f32
    const float* E = (const float*)d_in[1];   // [8192, 64]  f32
    float* out = (float*)d_out;
    char* ws = (char*)d_ws;

    float*     n_   = (float*)(ws + 0);          // 32 KB
    float*     ne   = (float*)(ws + 32768);      // 32 KB
    float*     Z    = (float*)(ws + 65536);      // 32 KB (init 1.0 in k_prep)
    float*     num  = (float*)(ws + 98304);      // 32 KB (memset 0)
    double*    part = (double*)(ws + 131072);    // 256 B
    _Float16*  Eh   = (_Float16*)(ws + 131584);  // 1 MB
    _Float16*  Er   = (_Float16*)(ws + 1180160); // 1 MB
    _Float16*  Vh   = (_Float16*)(ws + 2228736); // 8 MB

    hipMemsetAsync((void*)num, 0, 32768, stream);

    k_prep  <<<2048, 256, 0, stream>>>(V, E, n_, ne, Z, Eh, Er, Vh);
    k_mega  <<<2080, 256, 0, stream>>>(Eh, Er, Vh, ne, n_, Z, num);
    k_final1<<<32, 256, 0, stream>>>(Z, num, part);
    k_final2<<<1, 64, 0, stream>>>(part, out);
}